// Round 1
// baseline (437.689 us; speedup 1.0000x reference)
//
#include <hip/hip_runtime.h>
#include <stdint.h>

#define ROWS 32
#define ROWLEN (96*128*128)            // 1,572,864 elements per (b,c) row
#define BINS 2048
#define CHUNK 4096                     // elements per block in pass A/C
#define SEGS_PER_ROW (ROWLEN / CHUNK)  // 384
#define WSEG_PER_ROW (SEGS_PER_ROW*4)  // per-wave segments: 1536
#define CAP 4096                       // candidate capacity per row
#define HW_ (128*128)                  // 16384
#define W_ 128

__device__ __forceinline__ unsigned keyOf(float f) {
    unsigned u = __float_as_uint(f);
    // order-preserving: larger float -> larger unsigned key
    return (u & 0x80000000u) ? ~u : (u | 0x80000000u);
}

// ---------------- Pass A: per-row 2048-bin histogram + per-wave-chunk max ----
__global__ __launch_bounds__(256) void hist_kernel(const float4* __restrict__ in,
                                                   unsigned* __restrict__ hist,
                                                   float* __restrict__ segMax) {
    __shared__ unsigned h[BINS];
    const int tid = threadIdx.x;
    for (int i = tid; i < BINS; i += 256) h[i] = 0u;
    __syncthreads();

    const int row = blockIdx.x / SEGS_PER_ROW;
    const int seg = blockIdx.x % SEGS_PER_ROW;
    const float4* p = in + (size_t)row * (ROWLEN/4) + (size_t)seg * (CHUNK/4);

    float lmax = -INFINITY;
    #pragma unroll
    for (int j = 0; j < 4; j++) {
        float4 v = p[j*256 + tid];
        float a0 = v.x, a1 = v.y, a2 = v.z, a3 = v.w;
        atomicAdd(&h[keyOf(a0) >> 21], 1u);
        atomicAdd(&h[keyOf(a1) >> 21], 1u);
        atomicAdd(&h[keyOf(a2) >> 21], 1u);
        atomicAdd(&h[keyOf(a3) >> 21], 1u);
        lmax = fmaxf(lmax, fmaxf(fmaxf(a0, a1), fmaxf(a2, a3)));
    }
    // per-wave max (64 lanes)
    #pragma unroll
    for (int off = 32; off; off >>= 1) lmax = fmaxf(lmax, __shfl_xor(lmax, off));
    if ((tid & 63) == 0)
        segMax[(size_t)row * WSEG_PER_ROW + seg*4 + (tid >> 6)] = lmax;

    __syncthreads();
    unsigned* gh = hist + (size_t)row * BINS;
    for (int i = tid; i < BINS; i += 256) {
        unsigned c = h[i];
        if (c) atomicAdd(&gh[i], c);
    }
}

// ---------------- Pass B: find per-row threshold key (bin of the 64th value) -
__global__ __launch_bounds__(256) void threshold_kernel(const unsigned* __restrict__ hist,
                                                        unsigned* __restrict__ thrKey) {
    const int row = blockIdx.x;
    const int tid = threadIdx.x;
    __shared__ unsigned s[256];
    __shared__ int cross;

    const unsigned* hr = hist + (size_t)row * BINS;
    unsigned local[8];
    unsigned part = 0;
    #pragma unroll
    for (int j = 0; j < 8; j++) { local[j] = hr[tid*8 + j]; part += local[j]; }
    s[tid] = part;
    if (tid == 0) cross = -1;
    __syncthreads();

    // inclusive suffix scan: s[i] = sum_{j>=i} part_j
    for (int d = 1; d < 256; d <<= 1) {
        unsigned add = (tid + d < 256) ? s[tid + d] : 0u;
        __syncthreads();
        s[tid] += add;
        __syncthreads();
    }

    unsigned Sc = s[tid];
    unsigned Snext = (tid < 255) ? s[tid + 1] : 0u;
    if (Sc >= 64u && (tid == 255 || Snext < 64u)) cross = tid;  // unique (s is non-increasing)
    __syncthreads();

    if (tid == cross) {
        unsigned cum = Snext;
        int bin = tid * 8;  // fallback (always overwritten below)
        #pragma unroll
        for (int j = 7; j >= 0; j--) {
            cum += local[j];
            if (cum >= 64u) { bin = tid*8 + j; break; }
        }
        thrKey[row] = ((unsigned)bin) << 21;
    }
}

// ---------------- Pass C: collect (value, index) of all elements >= threshold
__global__ __launch_bounds__(256) void collect_kernel(const float4* __restrict__ in,
                                                      const unsigned* __restrict__ thrKey,
                                                      const float* __restrict__ segMax,
                                                      unsigned* __restrict__ candCount,
                                                      float* __restrict__ candVal,
                                                      int* __restrict__ candIdx) {
    const int tid = threadIdx.x;
    const int row = blockIdx.x / SEGS_PER_ROW;
    const int seg = blockIdx.x % SEGS_PER_ROW;
    const unsigned thr = thrKey[row];

    // whole-wave skip if this wave's chunk can't contain a candidate
    const int wave = tid >> 6;
    float smax = segMax[(size_t)row * WSEG_PER_ROW + seg*4 + wave];
    if (keyOf(smax) < thr) return;

    const float4* p = in + (size_t)row * (ROWLEN/4) + (size_t)seg * (CHUNK/4);
    #pragma unroll
    for (int j = 0; j < 4; j++) {
        float4 v = p[j*256 + tid];
        float a[4] = {v.x, v.y, v.z, v.w};
        #pragma unroll
        for (int c = 0; c < 4; c++) {
            if (keyOf(a[c]) >= thr) {
                unsigned pos = atomicAdd(&candCount[row], 1u);
                if (pos < CAP) {
                    candVal[(size_t)row * CAP + pos] = a[c];
                    candIdx[(size_t)row * CAP + pos] = (seg*(CHUNK/4) + j*256 + tid)*4 + c;
                }
            }
        }
    }
}

// ---------------- Pass D: exact top-64 among candidates, softmax, weighted coords
__global__ __launch_bounds__(256) void finalize_kernel(const unsigned* __restrict__ candCount,
                                                       const float* __restrict__ candVal,
                                                       const int* __restrict__ candIdx,
                                                       float* __restrict__ out) {
    const int row = blockIdx.x;
    const int tid = threadIdx.x;
    __shared__ float v[CAP];
    __shared__ int   id[CAP];
    __shared__ float topV[64];
    __shared__ int   topI[64];
    __shared__ float wmax[4];
    __shared__ int   wpos[4];

    int n = (int)candCount[row];
    if (n > CAP) n = CAP;
    for (int i = tid; i < n; i += 256) {
        v[i]  = candVal[(size_t)row * CAP + i];
        id[i] = candIdx[(size_t)row * CAP + i];
    }
    __syncthreads();

    const int k = (n < 64) ? n : 64;
    for (int r = 0; r < k; r++) {
        float bm = -INFINITY; int bp = -1;
        for (int i = tid; i < n; i += 256) {
            float x = v[i];
            if (x > bm) { bm = x; bp = i; }
        }
        #pragma unroll
        for (int off = 32; off; off >>= 1) {
            float om = __shfl_down(bm, off);
            int   op = __shfl_down(bp, off);
            if (om > bm) { bm = om; bp = op; }
        }
        if ((tid & 63) == 0) { wmax[tid >> 6] = bm; wpos[tid >> 6] = bp; }
        __syncthreads();
        if (tid == 0) {
            float m = wmax[0]; int p = wpos[0];
            #pragma unroll
            for (int w = 1; w < 4; w++) if (wmax[w] > m) { m = wmax[w]; p = wpos[w]; }
            topV[r] = m; topI[r] = id[p];
            v[p] = -INFINITY;
        }
        __syncthreads();
    }

    // softmax + weighted coordinate sum in wave 0
    if (tid < 64) {
        float val = (tid < k) ? topV[tid] : -INFINITY;
        float m = val;
        #pragma unroll
        for (int off = 32; off; off >>= 1) m = fmaxf(m, __shfl_xor(m, off));
        float e = 0.0f;
        int index = 0;
        if (tid < k) { e = expf((val - m) * 10.0f); index = topI[tid]; }
        float fd = (float)(index / HW_);
        int rem = index % HW_;
        float fh = (float)(rem / W_);
        float fw = (float)(rem % W_);
        float se = e, sd = e * fd, sh = e * fh, sw = e * fw;
        #pragma unroll
        for (int off = 32; off; off >>= 1) {
            se += __shfl_xor(se, off);
            sd += __shfl_xor(sd, off);
            sh += __shfl_xor(sh, off);
            sw += __shfl_xor(sw, off);
        }
        if (tid == 0) {
            float inv = 1.0f / (se + 1e-20f);
            out[row*3 + 0] = sd * inv;
            out[row*3 + 1] = sh * inv;
            out[row*3 + 2] = sw * inv;
        }
    }
}

extern "C" void kernel_launch(void* const* d_in, const int* in_sizes, int n_in,
                              void* d_out, int out_size, void* d_ws, size_t ws_size,
                              hipStream_t stream) {
    const float* heat = (const float*)d_in[0];
    float* out = (float*)d_out;

    uint8_t* base = (uint8_t*)d_ws;
    // layout:
    //   [0,       262144)  hist      32*2048*u32
    //   [262144,  262272)  candCount 32*u32
    //   [262272,  262400)  thrKey    32*u32
    //   [262400,  459008)  segMax    49152*f32
    //   [459008,  983296)  candVal   32*4096*f32
    //   [983296, 1507584)  candIdx   32*4096*i32
    unsigned* hist      = (unsigned*)(base);
    unsigned* candCount = (unsigned*)(base + 262144);
    unsigned* thrKey    = (unsigned*)(base + 262272);
    float*    segMax    = (float*)(base + 262400);
    float*    candVal   = (float*)(base + 459008);
    int*      candIdx   = (int*)(base + 983296);

    // zero hist + candCount (ws is re-poisoned to 0xAA before every launch)
    hipMemsetAsync(base, 0, 262272, stream);

    hipLaunchKernelGGL(hist_kernel, dim3(ROWS * SEGS_PER_ROW), dim3(256), 0, stream,
                       (const float4*)heat, hist, segMax);
    hipLaunchKernelGGL(threshold_kernel, dim3(ROWS), dim3(256), 0, stream, hist, thrKey);
    hipLaunchKernelGGL(collect_kernel, dim3(ROWS * SEGS_PER_ROW), dim3(256), 0, stream,
                       (const float4*)heat, thrKey, segMax, candCount, candVal, candIdx);
    hipLaunchKernelGGL(finalize_kernel, dim3(ROWS), dim3(256), 0, stream,
                       candCount, candVal, candIdx, out);
}

// Round 2
// 393.897 us; speedup vs baseline: 1.1112x; 1.1112x over previous
//
#include <hip/hip_runtime.h>
#include <stdint.h>

#define ROWS 32
#define ROWLEN (96*128*128)            // 1,572,864 elements per (b,c) row
#define SEG 1024                       // elements per wave-segment
#define SEGS_PER_ROW (ROWLEN / SEG)    // 1536
#define NSEG_TOTAL (ROWS * SEGS_PER_ROW) // 49152
#define SEGS_PER_WAVE 12
#define NWAVES (NSEG_TOTAL / SEGS_PER_WAVE) // 4096
#define NBLOCKS_SCAN (NWAVES / 4)      // 1024 blocks of 256 threads
#define CAP 4096                       // candidate capacity per row
#define CNT_STRIDE 32                  // pad row counters to 128B lines
#define HW_ (128*128)
#define W_ 128

__device__ __forceinline__ unsigned keyOf(float f) {
    unsigned u = __float_as_uint(f);
    return (u & 0x80000000u) ? ~u : (u | 0x80000000u); // order-preserving
}

// ---- Pass A: pure streaming scan, per-1024-element segment max -------------
__global__ __launch_bounds__(256) void scan_kernel(const float4* __restrict__ in,
                                                   float* __restrict__ segMax) {
    const int wid  = (blockIdx.x * 256 + threadIdx.x) >> 6;  // 0..4095
    const int lane = threadIdx.x & 63;
    const int s0 = wid * SEGS_PER_WAVE;

    #pragma unroll 2
    for (int t = 0; t < SEGS_PER_WAVE; ++t) {
        const float4* p = in + (size_t)(s0 + t) * (SEG/4) + lane;
        float4 a = p[0], b = p[64], c = p[128], d = p[192];
        float m = fmaxf(fmaxf(fmaxf(a.x, a.y), fmaxf(a.z, a.w)),
                        fmaxf(fmaxf(b.x, b.y), fmaxf(b.z, b.w)));
        m = fmaxf(m, fmaxf(fmaxf(c.x, c.y), fmaxf(c.z, c.w)));
        m = fmaxf(m, fmaxf(fmaxf(d.x, d.y), fmaxf(d.z, d.w)));
        #pragma unroll
        for (int off = 32; off; off >>= 1) m = fmaxf(m, __shfl_xor(m, off));
        if (lane == 0) segMax[s0 + t] = m;
    }
}

// ---- Pass B: per row, 64th largest segMax -> threshold; zero counters ------
__global__ __launch_bounds__(64) void threshold_kernel(const float* __restrict__ segMax,
                                                       unsigned* __restrict__ thrKey,
                                                       unsigned* __restrict__ candCount) {
    const int row = blockIdx.x;
    const int lane = threadIdx.x;
    __shared__ float v[SEGS_PER_ROW];

    for (int i = lane; i < SEGS_PER_ROW; i += 64)
        v[i] = segMax[(size_t)row * SEGS_PER_ROW + i];
    __syncthreads();

    float thr = -INFINITY;
    for (int r = 0; r < 64; ++r) {
        float bm = -INFINITY; int bp = -1;
        for (int i = lane; i < SEGS_PER_ROW; i += 64) {
            float x = v[i];
            if (x > bm) { bm = x; bp = i; }
        }
        #pragma unroll
        for (int off = 32; off; off >>= 1) {
            float om = __shfl_xor(bm, off);
            int   op = __shfl_xor(bp, off);
            if (om > bm || (om == bm && op >= 0 && (bp < 0 || op < bp))) { bm = om; bp = op; }
        }
        thr = bm;
        if (lane == 0 && bp >= 0) v[bp] = -INFINITY;
        __syncthreads();
    }
    if (lane == 0) {
        thrKey[row] = keyOf(thr);
        candCount[row * CNT_STRIDE] = 0u;
    }
}

// ---- Pass C: collect elements >= threshold (wave-skip + one atomic/segment) -
__global__ __launch_bounds__(256) void collect_kernel(const float4* __restrict__ in,
                                                      const float* __restrict__ segMax,
                                                      const unsigned* __restrict__ thrKey,
                                                      unsigned* __restrict__ candCount,
                                                      float* __restrict__ candVal,
                                                      int* __restrict__ candIdx) {
    const int wid  = (blockIdx.x * 256 + threadIdx.x) >> 6;
    const int lane = threadIdx.x & 63;
    const int s0 = wid * SEGS_PER_WAVE;
    const int row = s0 / SEGS_PER_ROW;      // 12 | 1536 -> whole wave same row
    const unsigned thr = thrKey[row];

    for (int t = 0; t < SEGS_PER_WAVE; ++t) {
        const int s = s0 + t;
        if (keyOf(segMax[s]) < thr) continue;   // wave-uniform skip, no data read

        const float4* p = in + (size_t)s * (SEG/4) + lane;
        float4 q0 = p[0], q1 = p[64], q2 = p[128], q3 = p[192];
        float vals[16] = {q0.x,q0.y,q0.z,q0.w, q1.x,q1.y,q1.z,q1.w,
                          q2.x,q2.y,q2.z,q2.w, q3.x,q3.y,q3.z,q3.w};
        unsigned long long m[16];
        unsigned tot = 0;
        #pragma unroll
        for (int e = 0; e < 16; ++e) {
            m[e] = __ballot(keyOf(vals[e]) >= thr);
            tot += (unsigned)__popcll(m[e]);
        }
        if (tot == 0) continue;                 // wave-uniform

        int basei = 0;
        if (lane == 0) basei = (int)atomicAdd(&candCount[row * CNT_STRIDE], tot);
        basei = __shfl(basei, 0);

        const unsigned long long below = (1ull << lane) - 1ull;
        unsigned pre = 0;
        #pragma unroll
        for (int e = 0; e < 16; ++e) {
            if ((m[e] >> lane) & 1ull) {
                unsigned pos = (unsigned)basei + pre + (unsigned)__popcll(m[e] & below);
                if (pos < CAP) {
                    const int j = e >> 2, c = e & 3;
                    candVal[(size_t)row * CAP + pos] = vals[e];
                    candIdx[(size_t)row * CAP + pos] =
                        (s - row * SEGS_PER_ROW) * SEG + (j * 64 + lane) * 4 + c;
                }
            }
            pre += (unsigned)__popcll(m[e]);
        }
    }
}

// ---- Pass D: exact top-64 among candidates, softmax, weighted coords -------
__global__ __launch_bounds__(64) void finalize_kernel(const unsigned* __restrict__ candCount,
                                                      const float* __restrict__ candVal,
                                                      const int* __restrict__ candIdx,
                                                      float* __restrict__ out) {
    const int row = blockIdx.x;
    const int lane = threadIdx.x;
    __shared__ float v[CAP];
    __shared__ int   id[CAP];

    int n = (int)candCount[row * CNT_STRIDE];
    if (n > CAP) n = CAP;
    for (int i = lane; i < n; i += 64) {
        v[i]  = candVal[(size_t)row * CAP + i];
        id[i] = candIdx[(size_t)row * CAP + i];
    }
    __syncthreads();

    float tv = -INFINITY; int ti = 0;
    for (int r = 0; r < 64; ++r) {
        float bm = -INFINITY; int bp = -1;
        for (int i = lane; i < n; i += 64) {
            float x = v[i];
            if (x > bm) { bm = x; bp = i; }
        }
        #pragma unroll
        for (int off = 32; off; off >>= 1) {
            float om = __shfl_xor(bm, off);
            int   op = __shfl_xor(bp, off);
            if (om > bm || (om == bm && op >= 0 && (bp < 0 || op < bp))) { bm = om; bp = op; }
        }
        if (lane == r) { tv = bm; ti = (bp >= 0) ? id[bp] : 0; }
        if (lane == 0 && bp >= 0) v[bp] = -INFINITY;
        __syncthreads();
    }

    // softmax over the 64 selected (lane r holds r-th), weighted coord sum
    float mmax = tv;
    #pragma unroll
    for (int off = 32; off; off >>= 1) mmax = fmaxf(mmax, __shfl_xor(mmax, off));
    float e = (tv == -INFINITY) ? 0.0f : expf((tv - mmax) * 10.0f);  // /TEMPERATURE=×10
    float fd = (float)(ti / HW_);
    int rem = ti % HW_;
    float fh = (float)(rem / W_);
    float fw = (float)(rem % W_);
    float se = e, sd = e * fd, sh = e * fh, sw = e * fw;
    #pragma unroll
    for (int off = 32; off; off >>= 1) {
        se += __shfl_xor(se, off);
        sd += __shfl_xor(sd, off);
        sh += __shfl_xor(sh, off);
        sw += __shfl_xor(sw, off);
    }
    if (lane == 0) {
        float inv = 1.0f / (se + 1e-20f);
        out[row * 3 + 0] = sd * inv;
        out[row * 3 + 1] = sh * inv;
        out[row * 3 + 2] = sw * inv;
    }
}

extern "C" void kernel_launch(void* const* d_in, const int* in_sizes, int n_in,
                              void* d_out, int out_size, void* d_ws, size_t ws_size,
                              hipStream_t stream) {
    const float* heat = (const float*)d_in[0];
    float* out = (float*)d_out;

    uint8_t* base = (uint8_t*)d_ws;
    // layout (bytes):
    //   [0,      196608)  segMax    49152*f32
    //   [196608, 196736)  thrKey    32*u32
    //   [196736, 200832)  candCount 32 rows, stride 32*u32 (128B lines)
    //   [200832, 725120)  candVal   32*4096*f32
    //   [725120, 1249408) candIdx   32*4096*i32
    float*    segMax    = (float*)(base);
    unsigned* thrKey    = (unsigned*)(base + 196608);
    unsigned* candCount = (unsigned*)(base + 196736);
    float*    candVal   = (float*)(base + 200832);
    int*      candIdx   = (int*)(base + 725120);

    hipLaunchKernelGGL(scan_kernel, dim3(NBLOCKS_SCAN), dim3(256), 0, stream,
                       (const float4*)heat, segMax);
    hipLaunchKernelGGL(threshold_kernel, dim3(ROWS), dim3(64), 0, stream,
                       segMax, thrKey, candCount);
    hipLaunchKernelGGL(collect_kernel, dim3(NBLOCKS_SCAN), dim3(256), 0, stream,
                       (const float4*)heat, segMax, thrKey, candCount, candVal, candIdx);
    hipLaunchKernelGGL(finalize_kernel, dim3(ROWS), dim3(64), 0, stream,
                       candCount, candVal, candIdx, out);
}

// Round 5
// 344.942 us; speedup vs baseline: 1.2689x; 1.1419x over previous
//
#include <hip/hip_runtime.h>
#include <stdint.h>

#define ROWS 32
#define ROWLEN (96*128*128)              // 1,572,864 elements per (b,c) row
#define SEG 1024                         // elements per segment
#define SEGS_PER_ROW (ROWLEN / SEG)      // 1536
#define NSEG_TOTAL (ROWS * SEGS_PER_ROW) // 49152
#define SEGS_PER_WAVE 6
#define NWAVES (NSEG_TOTAL / SEGS_PER_WAVE) // 8192
#define NBLOCKS_SCAN (NWAVES / 4)        // 2048 blocks x 256 thr = 8/CU
#define NGROUPS 64
#define GRPSZ (SEGS_PER_ROW / NGROUPS)   // 24
#define CAP 8192                         // candidate capacity (LDS)
#define HW_ (128*128)
#define W_ 128

// ---- Pass A: pure streaming scan, per-1024-element segment max -------------
__global__ __launch_bounds__(256) void scan_kernel(const float4* __restrict__ in,
                                                   float* __restrict__ segMax) {
    const int wid  = (blockIdx.x * 256 + threadIdx.x) >> 6;  // 0..8191
    const int lane = threadIdx.x & 63;
    const int s0 = wid * SEGS_PER_WAVE;

    #pragma unroll
    for (int t = 0; t < SEGS_PER_WAVE; ++t) {
        const float4* p = in + (size_t)(s0 + t) * (SEG/4) + lane;
        float4 a = p[0], b = p[64], c = p[128], d = p[192];
        float m = fmaxf(fmaxf(fmaxf(a.x, a.y), fmaxf(a.z, a.w)),
                        fmaxf(fmaxf(b.x, b.y), fmaxf(b.z, b.w)));
        m = fmaxf(m, fmaxf(fmaxf(c.x, c.y), fmaxf(c.z, c.w)));
        m = fmaxf(m, fmaxf(fmaxf(d.x, d.y), fmaxf(d.z, d.w)));
        #pragma unroll
        for (int off = 32; off; off >>= 1) m = fmaxf(m, __shfl_xor(m, off));
        if (lane == 0) segMax[s0 + t] = m;
    }
}

// ---- Pass B: per row — threshold, collect, exact top-64, softmax, coords ---
__global__ __launch_bounds__(1024) void select_kernel(const float4* __restrict__ in,
                                                      const float* __restrict__ segMax,
                                                      float* __restrict__ out) {
    const int row = blockIdx.x;
    const int tid = threadIdx.x;
    const int wav = tid >> 6, lane = tid & 63;

    __shared__ float sm[SEGS_PER_ROW];
    __shared__ int   surv[SEGS_PER_ROW];
    __shared__ int   nSurv, nCand;
    __shared__ float Tsh;
    __shared__ float candV[CAP];
    __shared__ int   candI[CAP];
    __shared__ float topV[64];
    __shared__ int   topI[64];

    for (int i = tid; i < SEGS_PER_ROW; i += 1024)
        sm[i] = segMax[(size_t)row * SEGS_PER_ROW + i];
    if (tid == 0) { nSurv = 0; nCand = 0; }
    __syncthreads();

    // Threshold T = min over 64 group-maxima (groups of 24 segMaxes).
    // The 64 group maxima are 64 distinct elements >= T, so e64 >= T and
    // every true top-64 element is >= T.  (wave 0 only)
    if (tid < NGROUPS) {
        float m = -INFINITY;
        #pragma unroll
        for (int j = 0; j < GRPSZ; ++j) m = fmaxf(m, sm[tid * GRPSZ + j]);
        #pragma unroll
        for (int off = 32; off; off >>= 1) m = fminf(m, __shfl_xor(m, off));
        if (tid == 0) Tsh = m;
    }
    __syncthreads();
    const float T = Tsh;

    // Survivor segment list (segMax >= T): ~250 of 1536
    for (int i = tid; i < SEGS_PER_ROW; i += 1024)
        if (sm[i] >= T) { int p = atomicAdd(&nSurv, 1); surv[p] = i; }
    __syncthreads();

    // Collect candidates: one wave per surviving segment (reads hit L3)
    const int ns = nSurv;
    for (int si = wav; si < ns; si += 16) {
        const int s = surv[si];
        const float4* p = in + ((size_t)row * SEGS_PER_ROW + s) * (SEG/4) + lane;
        #pragma unroll
        for (int j = 0; j < 4; ++j) {
            float4 q = p[j * 64];
            float a[4] = {q.x, q.y, q.z, q.w};
            #pragma unroll
            for (int c = 0; c < 4; ++c) {
                if (a[c] >= T) {
                    int pos = atomicAdd(&nCand, 1);
                    if (pos < CAP) {
                        candV[pos] = a[c];
                        candI[pos] = s * SEG + (j * 64 + lane) * 4 + c;
                    }
                }
            }
        }
    }
    __syncthreads();
    int n = nCand; if (n > CAP) n = CAP;   // n >= 64 guaranteed (group maxima)

    // Exact top-64 by rank-counting over n (~300) candidates.
    // Order: value desc, index asc — matches jax.lax.top_k tie-breaking.
    for (int i = tid; i < n; i += 1024) {
        const float vi = candV[i];
        const int   ii = candI[i];
        int rank = 0;
        for (int j = 0; j < n; ++j) {
            const float vj = candV[j];               // lockstep -> LDS broadcast
            rank += (vj > vi) || (vj == vi && candI[j] < ii);
        }
        if (rank < 64) { topV[rank] = vi; topI[rank] = ii; }
    }
    __syncthreads();

    // Wave 0: temperature softmax over the 64 + weighted coordinate sums
    if (tid < 64) {
        const float v = topV[tid];
        const int idx = topI[tid];
        float m = v;
        #pragma unroll
        for (int off = 32; off; off >>= 1) m = fmaxf(m, __shfl_xor(m, off));
        const float e = expf((v - m) * 10.0f);       // /TEMPERATURE = x10
        const float fd = (float)(idx / HW_);
        const int rem = idx % HW_;
        const float fh = (float)(rem / W_);
        const float fw = (float)(rem % W_);
        float se = e, sd = e * fd, sh = e * fh, sw = e * fw;
        #pragma unroll
        for (int off = 32; off; off >>= 1) {
            se += __shfl_xor(se, off);
            sd += __shfl_xor(sd, off);
            sh += __shfl_xor(sh, off);
            sw += __shfl_xor(sw, off);
        }
        if (tid == 0) {
            const float inv = 1.0f / (se + 1e-20f);
            out[row * 3 + 0] = sd * inv;
            out[row * 3 + 1] = sh * inv;
            out[row * 3 + 2] = sw * inv;
        }
    }
}

extern "C" void kernel_launch(void* const* d_in, const int* in_sizes, int n_in,
                              void* d_out, int out_size, void* d_ws, size_t ws_size,
                              hipStream_t stream) {
    const float* heat = (const float*)d_in[0];
    float* out = (float*)d_out;
    float* segMax = (float*)d_ws;   // 49152 * f32 = 196 KB, fully overwritten

    hipLaunchKernelGGL(scan_kernel, dim3(NBLOCKS_SCAN), dim3(256), 0, stream,
                       (const float4*)heat, segMax);
    hipLaunchKernelGGL(select_kernel, dim3(ROWS), dim3(1024), 0, stream,
                       (const float4*)heat, segMax, out);
}

// Round 6
// 308.956 us; speedup vs baseline: 1.4167x; 1.1165x over previous
//
#include <hip/hip_runtime.h>
#include <stdint.h>

#define ROWS 32
#define ROWLEN (96*128*128)              // 1,572,864 elements per (b,c) row
#define SEG 1024                         // elements per segment
#define SEGS_PER_ROW (ROWLEN / SEG)      // 1536
#define NSEG_TOTAL (ROWS * SEGS_PER_ROW) // 49152
#define SEGS_PER_WAVE 6
#define NWAVES (NSEG_TOTAL / SEGS_PER_WAVE) // 8192
#define NBLOCKS_SCAN (NWAVES / 4)        // 2048 blocks x 256 thr
#define NGROUPS 64
#define GRPSZ (SEGS_PER_ROW / NGROUPS)   // 24
#define CAP 8192                         // candidate capacity (LDS)
#define HW_ (128*128)
#define W_ 128

// ---- Pass A: streaming scan; per-segment (max, argmax, 2nd-max) ------------
__global__ __launch_bounds__(256) void scan_kernel(const float4* __restrict__ in,
                                                   float* __restrict__ segMax,
                                                   float* __restrict__ segMax2,
                                                   int* __restrict__ segIdx) {
    const int wid  = (blockIdx.x * 256 + threadIdx.x) >> 6;  // 0..8191
    const int lane = threadIdx.x & 63;
    const int s0 = wid * SEGS_PER_WAVE;

    for (int t = 0; t < SEGS_PER_WAVE; ++t) {
        const int s = s0 + t;
        const float4* p = in + (size_t)s * (SEG/4) + lane;
        float m1 = -INFINITY, m2 = -INFINITY;
        int i1 = 0;
        #pragma unroll
        for (int j = 0; j < 4; ++j) {
            float4 q = p[j * 64];
            float a[4] = {q.x, q.y, q.z, q.w};
            #pragma unroll
            for (int c = 0; c < 4; ++c) {
                const float v = a[c];
                const int idx = (j * 64 + lane) * 4 + c;   // index within segment
                if (v > m1)      { m2 = m1; m1 = v; i1 = idx; }
                else if (v > m2) { m2 = v; }
            }
        }
        // wave-reduce (m1,i1,m2); argmax tie-break: smaller index wins
        #pragma unroll
        for (int off = 32; off; off >>= 1) {
            const float o1 = __shfl_xor(m1, off);
            const float o2 = __shfl_xor(m2, off);
            const int   oi = __shfl_xor(i1, off);
            const float n2 = fmaxf(fminf(m1, o1), fmaxf(m2, o2)); // 2nd of union
            const bool  gt = (o1 > m1) || (o1 == m1 && oi < i1);
            if (gt) { m1 = o1; i1 = oi; }
            m2 = n2;
        }
        if (lane == 0) { segMax[s] = m1; segMax2[s] = m2; segIdx[s] = i1; }
    }
}

// ---- Pass B: per row — threshold, gather, exact top-64, softmax, coords ----
__global__ __launch_bounds__(1024) void select_kernel(const float4* __restrict__ in,
                                                      const float* __restrict__ segMax,
                                                      const float* __restrict__ segMax2,
                                                      const int* __restrict__ segIdx,
                                                      float* __restrict__ out) {
    const int row = blockIdx.x;
    const int tid = threadIdx.x;
    const int wav = tid >> 6, lane = tid & 63;
    const int base = row * SEGS_PER_ROW;

    __shared__ float sm[SEGS_PER_ROW];
    __shared__ int   surv[SEGS_PER_ROW];
    __shared__ int   nSurv, nCand;
    __shared__ float Tsh;
    __shared__ float candV[CAP];
    __shared__ int   candI[CAP];
    __shared__ float topV[64];
    __shared__ int   topI[64];

    for (int i = tid; i < SEGS_PER_ROW; i += 1024)
        sm[i] = segMax[base + i];
    if (tid == 0) { nSurv = 0; nCand = 0; }
    __syncthreads();

    // T = min over 64 group-maxima (groups of 24 segMaxes): the 64 group
    // maxima are 64 distinct elements >= T, so top-64 subset of {x >= T}.
    if (tid < NGROUPS) {
        float m = -INFINITY;
        #pragma unroll
        for (int j = 0; j < GRPSZ; ++j) m = fmaxf(m, sm[tid * GRPSZ + j]);
        #pragma unroll
        for (int off = 32; off; off >>= 1) m = fminf(m, __shfl_xor(m, off));
        if (tid == 0) Tsh = m;
    }
    __syncthreads();
    const float T = Tsh;

    // Classify survivor segments:
    //   max2 < T  -> exactly one element >= T: take (max, idx) from scan metadata
    //   max2 >= T -> needs re-read (rare: ~30/row)
    for (int i = tid; i < SEGS_PER_ROW; i += 1024) {
        if (sm[i] >= T) {
            if (segMax2[base + i] < T) {
                int p = atomicAdd(&nCand, 1);
                if (p < CAP) {
                    candV[p] = sm[i];
                    candI[p] = i * SEG + segIdx[base + i];
                }
            } else {
                int p = atomicAdd(&nSurv, 1);
                surv[p] = i;
            }
        }
    }
    __syncthreads();

    // Re-read multi-candidate segments (L3-resident), one wave per segment
    const int ns = nSurv;
    for (int si = wav; si < ns; si += 16) {
        const int s = surv[si];
        const float4* p = in + ((size_t)base + s) * (SEG/4) + lane;
        #pragma unroll
        for (int j = 0; j < 4; ++j) {
            float4 q = p[j * 64];
            float a[4] = {q.x, q.y, q.z, q.w};
            #pragma unroll
            for (int c = 0; c < 4; ++c) {
                if (a[c] >= T) {
                    int pos = atomicAdd(&nCand, 1);
                    if (pos < CAP) {
                        candV[pos] = a[c];
                        candI[pos] = s * SEG + (j * 64 + lane) * 4 + c;
                    }
                }
            }
        }
    }
    __syncthreads();
    int n = nCand; if (n > CAP) n = CAP;   // n >= 64 guaranteed (group maxima)

    // Exact top-64 by rank-counting (value desc, index asc = lax.top_k order)
    for (int i = tid; i < n; i += 1024) {
        const float vi = candV[i];
        const int   ii = candI[i];
        int rank = 0;
        for (int j = 0; j < n; ++j) {
            const float vj = candV[j];               // lockstep -> LDS broadcast
            rank += (vj > vi) || (vj == vi && candI[j] < ii);
        }
        if (rank < 64) { topV[rank] = vi; topI[rank] = ii; }
    }
    __syncthreads();

    // Wave 0: temperature softmax over the 64 + weighted coordinate sums
    if (tid < 64) {
        const float v = topV[tid];
        const int idx = topI[tid];
        float m = v;
        #pragma unroll
        for (int off = 32; off; off >>= 1) m = fmaxf(m, __shfl_xor(m, off));
        const float e = expf((v - m) * 10.0f);       // /TEMPERATURE = x10
        const float fd = (float)(idx / HW_);
        const int rem = idx % HW_;
        const float fh = (float)(rem / W_);
        const float fw = (float)(rem % W_);
        float se = e, sd = e * fd, sh = e * fh, sw = e * fw;
        #pragma unroll
        for (int off = 32; off; off >>= 1) {
            se += __shfl_xor(se, off);
            sd += __shfl_xor(sd, off);
            sh += __shfl_xor(sh, off);
            sw += __shfl_xor(sw, off);
        }
        if (tid == 0) {
            const float inv = 1.0f / (se + 1e-20f);
            out[row * 3 + 0] = sd * inv;
            out[row * 3 + 1] = sh * inv;
            out[row * 3 + 2] = sw * inv;
        }
    }
}

extern "C" void kernel_launch(void* const* d_in, const int* in_sizes, int n_in,
                              void* d_out, int out_size, void* d_ws, size_t ws_size,
                              hipStream_t stream) {
    const float* heat = (const float*)d_in[0];
    float* out = (float*)d_out;

    uint8_t* base = (uint8_t*)d_ws;
    // layout (bytes): segMax [0,196608) | segMax2 [196608,393216) | segIdx [393216,589824)
    float* segMax  = (float*)(base);
    float* segMax2 = (float*)(base + 196608);
    int*   segIdx  = (int*)(base + 393216);

    hipLaunchKernelGGL(scan_kernel, dim3(NBLOCKS_SCAN), dim3(256), 0, stream,
                       (const float4*)heat, segMax, segMax2, segIdx);
    hipLaunchKernelGGL(select_kernel, dim3(ROWS), dim3(1024), 0, stream,
                       (const float4*)heat, segMax, segMax2, segIdx, out);
}